// Round 12
// baseline (186.269 us; speedup 1.0000x reference)
//
#include <hip/hip_runtime.h>
#include <hip/hip_bf16.h>
#include <stdint.h>

// Problem constants
#define B_  4
#define T_  2048
#define C_  1024
#define H_  16
#define D_  64
#define BT  (B_*T_)     // 8192
#define KDIM 1024

typedef __attribute__((ext_vector_type(8))) short bf16x8;
typedef __attribute__((ext_vector_type(4))) float f32x4;

__device__ __forceinline__ unsigned short f2bf(float f) {
  union { float f; unsigned u; } v; v.f = f;
  unsigned r = v.u + 0x7FFFu + ((v.u >> 16) & 1u);   // RNE
  return (unsigned short)(r >> 16);
}

__device__ __forceinline__ float exp2_fast(float x) {   // raw v_exp_f32 (2^x)
  float r;
  asm("v_exp_f32 %0, %1" : "=v"(r) : "v"(x));
  return r;
}

// async global->LDS, 16B per lane. dest must be wave-uniform base + lane*16 (linear).
__device__ __forceinline__ void gld_lds16(const void* g, void* l) {
  __builtin_amdgcn_global_load_lds(
      (__attribute__((address_space(1))) unsigned int*)(uintptr_t)g,
      (__attribute__((address_space(3))) unsigned int*)(unsigned)(uintptr_t)l,
      16, 0, 0);
}

// ---------------------------------------------------------------- prep kernels
__global__ __launch_bounds__(256) void k_convert(
    const float* __restrict__ x,  const float* __restrict__ wq,
    const float* __restrict__ wk, const float* __restrict__ wv,
    const float* __restrict__ wp,
    unsigned short* __restrict__ xb, unsigned short* __restrict__ wcat,
    unsigned short* __restrict__ wpb)
{
  const int NX = BT*C_/4;       // 2097152 float4s of x
  const int NW = C_*C_/4;       // 262144 per W
  const int TOT = NX + 4*NW;
  for (int i = blockIdx.x*blockDim.x + threadIdx.x; i < TOT; i += gridDim.x*blockDim.x) {
    const float4* src; unsigned short* dst; int idx;
    if (i < NX)                { src = (const float4*)x;  dst = xb;            idx = i; }
    else {
      int j = i - NX;
      if (j < NW)              { src = (const float4*)wq; dst = wcat;          idx = j; }
      else if (j < 2*NW)       { src = (const float4*)wk; dst = wcat + C_*C_;  idx = j - NW; }
      else if (j < 3*NW)       { src = (const float4*)wv; dst = wcat + 2*C_*C_;idx = j - 2*NW; }
      else                     { src = (const float4*)wp; dst = wpb;           idx = j - 3*NW; }
    }
    float4 v = src[idx];
    ushort4 o; o.x = f2bf(v.x); o.y = f2bf(v.y); o.z = f2bf(v.z); o.w = f2bf(v.w);
    *(ushort4*)(dst + (size_t)idx*4) = o;
  }
}

// RoPE tables [T][D] (coalesced epilogue loads).
__global__ __launch_bounds__(256) void k_rope_tab(
    const int* __restrict__ start_pos, float* __restrict__ cosT, float* __restrict__ sinT)
{
  int i = blockIdx.x*blockDim.x + threadIdx.x;   // [0, T_*64)
  if (i >= T_*D_) return;
  int t = i >> 6, j = i & 63;
  float inv = exp2f(-(float)(j & 31) * (13.287712379549449f / 32.0f));
  float ang = (float)(t + start_pos[0]) * inv;
  cosT[i] = cosf(ang);
  sinT[i] = sinf(ang);
}

// ---------------------------------------------------------------- 256x256 8-wave GEMM, counted-vmcnt schedule
// (unchanged from R10/R11)
__global__ __launch_bounds__(512, 2) void k_gemm256(
    const unsigned short* __restrict__ A, const unsigned short* __restrict__ Bw,
    unsigned short* __restrict__ qb, unsigned short* __restrict__ kb,
    unsigned short* __restrict__ vt,
    const float* __restrict__ cosT, const float* __restrict__ sinT)
{
  __shared__ __attribute__((aligned(16))) char smem[131072];
  const int tid = threadIdx.x, l = tid & 63, w = tid >> 6;
  const int g = l >> 4, c = l & 15;
  const int m0 = blockIdx.x * 256, n0 = blockIdx.y * 256;
  const int wr = w >> 2, wc = w & 3;
  const char* gA = (const char*)A;
  const char* gB = (const char*)Bw;

  int dstU[2]; size_t aoff[2], boff[2];
#pragma unroll
  for (int j = 0; j < 2; ++j) {
    int P = j*8192 + tid*16;
    int p = P >> 7;
    int inner = (P & 127) ^ ((p & 7) << 4);
    int row = (p << 1) | (inner >> 6);
    int kc = (inner & 63) >> 1;
    dstU[j] = P;
    aoff[j] = ((size_t)(m0 + row) * KDIM + kc) * 2;
    boff[j] = ((size_t)(n0 + row) * KDIM + kc) * 2;
  }

  const int swzo = ((((c & 1) << 6) | (g << 4)) ^ (((c >> 1) & 7) << 4));
  const int aB = (wr*64 + (c >> 1)) * 128 + swzo;
  const int bB = 32768 + (wc*32 + (c >> 1)) * 128 + swzo;

  f32x4 acc[8][4];
#pragma unroll
  for (int i = 0; i < 8; ++i)
#pragma unroll
    for (int j = 0; j < 4; ++j) acc[i][j] = (f32x4){0.f,0.f,0.f,0.f};

#pragma unroll
  for (int j = 0; j < 2; ++j) gld_lds16(gA + aoff[j],      smem +     0 + dstU[j]);
#pragma unroll
  for (int j = 0; j < 2; ++j) gld_lds16(gB + boff[j],      smem + 32768 + dstU[j]);
#pragma unroll
  for (int j = 0; j < 2; ++j) gld_lds16(gA + aoff[j] + 64, smem + 16384 + dstU[j]);
#pragma unroll
  for (int j = 0; j < 2; ++j) gld_lds16(gB + boff[j] + 64, smem + 49152 + dstU[j]);
  asm volatile("s_waitcnt vmcnt(4)" ::: "memory");
  __builtin_amdgcn_s_barrier();

#define MFMA16(MB)                                                               \
    __builtin_amdgcn_s_setprio(1);                                               \
    _Pragma("unroll")                                                            \
    for (int i2 = 0; i2 < 4; ++i2)                                               \
      _Pragma("unroll")                                                          \
      for (int ni = 0; ni < 4; ++ni)                                             \
        acc[(MB)+i2][ni] = __builtin_amdgcn_mfma_f32_16x16x32_bf16(              \
            af[i2], bk[ni], acc[(MB)+i2][ni], 0, 0, 0);                          \
    __builtin_amdgcn_s_setprio(0);

#define PRE_MFMA                                                                 \
    __builtin_amdgcn_s_barrier();                                                \
    asm volatile("s_waitcnt lgkmcnt(0)" ::: "memory");                           \
    __builtin_amdgcn_sched_barrier(0);

  bf16x8 af[4], bk[4];

#pragma unroll 2
  for (int t = 0; t < 15; ++t) {
    const int par = (t & 1) << 16;
    const int nxt = par ^ 65536;
    const size_t ko = (size_t)(t + 1) * 128;

#pragma unroll
    for (int i2 = 0; i2 < 4; ++i2) af[i2] = *(const bf16x8*)(smem + par + aB + i2*1024);
#pragma unroll
    for (int ni = 0; ni < 4; ++ni) bk[ni] = *(const bf16x8*)(smem + par + bB + ni*1024);
#pragma unroll
    for (int j = 0; j < 2; ++j) gld_lds16(gA + aoff[j] + ko, smem + nxt + dstU[j]);
    PRE_MFMA
    MFMA16(0)
    __builtin_amdgcn_s_barrier();

#pragma unroll
    for (int i2 = 0; i2 < 4; ++i2) af[i2] = *(const bf16x8*)(smem + par + aB + (4+i2)*1024);
#pragma unroll
    for (int j = 0; j < 2; ++j) gld_lds16(gB + boff[j] + ko, smem + nxt + 32768 + dstU[j]);
    PRE_MFMA
    MFMA16(4)
    asm volatile("s_waitcnt vmcnt(4)" ::: "memory");
    __builtin_amdgcn_s_barrier();

#pragma unroll
    for (int i2 = 0; i2 < 4; ++i2) af[i2] = *(const bf16x8*)(smem + par + 16384 + aB + i2*1024);
#pragma unroll
    for (int ni = 0; ni < 4; ++ni) bk[ni] = *(const bf16x8*)(smem + par + 16384 + bB + ni*1024);
#pragma unroll
    for (int j = 0; j < 2; ++j) gld_lds16(gA + aoff[j] + ko + 64, smem + nxt + 16384 + dstU[j]);
    PRE_MFMA
    MFMA16(0)
    __builtin_amdgcn_s_barrier();

#pragma unroll
    for (int i2 = 0; i2 < 4; ++i2) af[i2] = *(const bf16x8*)(smem + par + 16384 + aB + (4+i2)*1024);
#pragma unroll
    for (int j = 0; j < 2; ++j) gld_lds16(gB + boff[j] + ko + 64, smem + nxt + 49152 + dstU[j]);
    PRE_MFMA
    MFMA16(4)
    asm volatile("s_waitcnt vmcnt(4)" ::: "memory");
    __builtin_amdgcn_s_barrier();
  }

  {
    const int par = 65536;
#pragma unroll
    for (int i2 = 0; i2 < 4; ++i2) af[i2] = *(const bf16x8*)(smem + par + aB + i2*1024);
#pragma unroll
    for (int ni = 0; ni < 4; ++ni) bk[ni] = *(const bf16x8*)(smem + par + bB + ni*1024);
    PRE_MFMA
    MFMA16(0)
    __builtin_amdgcn_s_barrier();
#pragma unroll
    for (int i2 = 0; i2 < 4; ++i2) af[i2] = *(const bf16x8*)(smem + par + aB + (4+i2)*1024);
    PRE_MFMA
    MFMA16(4)
    asm volatile("s_waitcnt vmcnt(0)" ::: "memory");
    __builtin_amdgcn_s_barrier();
#pragma unroll
    for (int i2 = 0; i2 < 4; ++i2) af[i2] = *(const bf16x8*)(smem + par + 16384 + aB + i2*1024);
#pragma unroll
    for (int ni = 0; ni < 4; ++ni) bk[ni] = *(const bf16x8*)(smem + par + 16384 + bB + ni*1024);
    PRE_MFMA
    MFMA16(0)
    __builtin_amdgcn_s_barrier();
#pragma unroll
    for (int i2 = 0; i2 < 4; ++i2) af[i2] = *(const bf16x8*)(smem + par + 16384 + aB + (4+i2)*1024);
    PRE_MFMA
    MFMA16(4)
  }
#undef MFMA16
#undef PRE_MFMA

  // epilogue: fused RoPE; C layout: col = lane&15, row = g*4 + r
#pragma unroll
  for (int mi = 0; mi < 8; ++mi) {
#pragma unroll
    for (int ni = 0; ni < 4; ++ni) {
      const int mrow0 = m0 + wr*128 + mi*16 + g*4;
      const int ncol  = n0 + wc*64 + ni*16 + c;
      const int which = ncol >> 10;          // 0=q 1=k 2=v (block-uniform)
      const int d = ncol & 1023, h = d >> 6, dd = d & 63;
      const int b = mrow0 >> 11, t0 = mrow0 & 2047;
      if (which == 2) {
        ushort4 o;
        o.x = f2bf(acc[mi][ni][0]); o.y = f2bf(acc[mi][ni][1]);
        o.z = f2bf(acc[mi][ni][2]); o.w = f2bf(acc[mi][ni][3]);
        *(ushort4*)(vt + ((size_t)((b*H_ + h)*D_ + dd))*T_ + t0) = o;
      } else {
#pragma unroll
        for (int r = 0; r < 4; ++r) {
          float val = acc[mi][ni][r];
          float partner = __shfl_xor(val, 1);          // value at dd^1 (lane^1)
          float rot = (dd & 1) ? partner : -partner;   // interleaved rotate_half
          float cv = cosT[(t0 + r)*64 + dd], sv = sinT[(t0 + r)*64 + dd];
          float o = val*cv + rot*sv;
          size_t oidx = (((size_t)(b*H_ + h))*T_ + (t0 + r))*D_ + dd;
          if (which == 0) qb[oidx] = f2bf(o * 0.180336879f);
          else            kb[oidx] = f2bf(o);
        }
      }
    }
  }
}

// ---------------------------------------------------------------- GEMM (NT, bf16), 128x128
// (unchanged proven template; output projection, EPI=1)
template<int EPI>
__global__ __launch_bounds__(256) void k_gemm(
    const unsigned short* __restrict__ A, const unsigned short* __restrict__ Bw,
    unsigned short* __restrict__ qb, unsigned short* __restrict__ kb,
    unsigned short* __restrict__ vt,
    const float* __restrict__ cosT, const float* __restrict__ sinT,
    float* __restrict__ outF)
{
  __shared__ __attribute__((aligned(16))) char smem[32768];  // A:16K B:16K
  const int tid = threadIdx.x, l = tid & 63, w = tid >> 6;
  const int g = l >> 4, c = l & 15;
  const int m0 = blockIdx.x * 128, n0 = blockIdx.y * 128;
  const int wr = w >> 1, wc = w & 1;

  const char* srcA[4]; const char* srcB[4]; int dstP[4];
#pragma unroll
  for (int j = 0; j < 4; ++j) {
    int P = w*4096 + j*1024 + l*16;
    int row = P >> 7;
    int Lb = P ^ ((row & 7) << 4);
    int col = (Lb & 127) >> 1;
    dstP[j] = P;
    srcA[j] = (const char*)A  + ((size_t)(m0 + row) * KDIM + col) * 2;
    srcB[j] = (const char*)Bw + ((size_t)(n0 + row) * KDIM + col) * 2;
  }

  f32x4 acc[4][4];
#pragma unroll
  for (int i = 0; i < 4; ++i)
#pragma unroll
    for (int j = 0; j < 4; ++j) acc[i][j] = (f32x4){0.f,0.f,0.f,0.f};

  for (int kt = 0; kt < KDIM; kt += 64) {
#pragma unroll
    for (int j = 0; j < 4; ++j) {
      gld_lds16(srcA[j] + kt*2, smem + dstP[j]);
      gld_lds16(srcB[j] + kt*2, smem + 16384 + dstP[j]);
    }
    __syncthreads();
#pragma unroll
    for (int kk = 0; kk < 2; ++kk) {
      bf16x8 af[4], bw4[4];
#pragma unroll
      for (int mi = 0; mi < 4; ++mi) {
        int row = wr*64 + mi*16 + c;
        int Lb = row*128 + (kk*32 + g*8)*2;
        af[mi] = *(const bf16x8*)(smem + (Lb ^ ((row & 7) << 4)));
      }
#pragma unroll
      for (int ni = 0; ni < 4; ++ni) {
        int row = wc*64 + ni*16 + c;
        int Lb = row*128 + (kk*32 + g*8)*2;
        bw4[ni] = *(const bf16x8*)(smem + 16384 + (Lb ^ ((row & 7) << 4)));
      }
#pragma unroll
      for (int mi = 0; mi < 4; ++mi)
#pragma unroll
        for (int ni = 0; ni < 4; ++ni)
          acc[mi][ni] = __builtin_amdgcn_mfma_f32_16x16x32_bf16(af[mi], bw4[ni], acc[mi][ni], 0, 0, 0);
    }
    __syncthreads();
  }

#pragma unroll
  for (int mi = 0; mi < 4; ++mi) {
#pragma unroll
    for (int ni = 0; ni < 4; ++ni) {
      const int mrow0 = m0 + wr*64 + mi*16 + g*4;
      const int ncol  = n0 + wc*64 + ni*16 + c;
      if (EPI == 1) {
#pragma unroll
        for (int r = 0; r < 4; ++r)
          outF[(size_t)(mrow0 + r) * 1024 + ncol] = acc[mi][ni][r];
      } else {
        const int which = ncol >> 10;
        const int d = ncol & 1023, h = d >> 6, dd = d & 63;
        const int b = mrow0 >> 11, t0 = mrow0 & 2047;
        if (which == 2) {
          ushort4 o;
          o.x = f2bf(acc[mi][ni][0]); o.y = f2bf(acc[mi][ni][1]);
          o.z = f2bf(acc[mi][ni][2]); o.w = f2bf(acc[mi][ni][3]);
          *(ushort4*)(vt + ((size_t)((b*H_ + h)*D_ + dd))*T_ + t0) = o;
        } else {
#pragma unroll
          for (int r = 0; r < 4; ++r) {
            float val = acc[mi][ni][r];
            float partner = __shfl_xor(val, 1);
            float rot = (dd & 1) ? partner : -partner;
            float cv = cosT[(t0 + r)*64 + dd], sv = sinT[(t0 + r)*64 + dd];
            float o = val*cv + rot*sv;
            size_t oidx = (((size_t)(b*H_ + h))*T_ + (t0 + r))*D_ + dd;
            if (which == 0) qb[oidx] = f2bf(o * 0.180336879f);
            else            kb[oidx] = f2bf(o);
          }
        }
      }
    }
  }
}

// ---------------------------------------------------------------- flash attention
// R11 structure with three changes:
// (a) XCD-locality grid: grid (64,8), x = bh, y = pair. linear id = bh + 64*p
//     -> id%8 = bh%8 -> all 8 blocks of one bh land on ONE XCD; each XCD holds
//     8 bh x 512KB K/V = 4MB = its L2. Kills the 8x cross-XCD K/V duplication.
// (b) tree max-reduce (depth 4 instead of 16-deep serial fmax chain).
// (c) MFMA ones-row-sum: ls[mi] = mfma(ones, pb[mi], ls[mi]) replaces the
//     32-deep serial rs add chain; C-layout makes every lane's reg0 the full
//     64-kv sum for its q column (no epilogue shfl reduce).
__global__ __launch_bounds__(256) void k_attn(
    const unsigned short* __restrict__ qb, const unsigned short* __restrict__ kb,
    const unsigned short* __restrict__ vt, unsigned short* __restrict__ yb)
{
  __shared__ __attribute__((aligned(16))) char smem[65536]; // 3x(K8K+V8K) + P:16K
  const int tid = threadIdx.x, l = tid & 63, w = tid >> 6;
  const int g = l >> 4, c = l & 15;
  const int bh = blockIdx.x;                 // (a) bh on x -> XCD locality
  const int pidx = blockIdx.y;               // pair index 0..7
  const size_t bhO = (size_t)bh * T_ * D_;
  const int pbase = 49152 + w*4096;
  const int b = bh >> 4, h = bh & 15;

  bf16x8 vones;
#pragma unroll
  for (int i = 0; i < 8; ++i) vones[i] = (short)0x3F80;   // bf16 1.0

  const char* srcK[2]; const char* srcV[2]; int dstP2[2];
#pragma unroll
  for (int j = 0; j < 2; ++j) {
    int P = w*2048 + j*1024 + l*16;
    int row = P >> 7;
    int Lb = P ^ ((row & 7) << 4);
    int col = (Lb & 127) >> 1;
    dstP2[j] = P;
    srcK[j] = (const char*)(kb + bhO) + ((size_t)row*D_ + col)*2;
    srcV[j] = (const char*)(vt + bhO) + ((size_t)row*T_ + col)*2;
  }

  for (int half = 0; half < 2; ++half) {
    const int qt = half ? pidx : (15 - pidx);
    const int q0 = qt * 128;
    const int q0w = q0 + w*32;

    bf16x8 aq[2][2];
#pragma unroll
    for (int mi = 0; mi < 2; ++mi)
#pragma unroll
      for (int kc = 0; kc < 2; ++kc) {
        int row = q0w + mi*16 + c;
        aq[mi][kc] = *(const bf16x8*)(qb + bhO + (size_t)row*D_ + kc*32 + g*8);
      }

    f32x4 po[4][2];
    f32x4 ls[2];                  // (c) MFMA row-sum accumulator (reg0 = full sum)
    float mrun[2];
#pragma unroll
    for (int nd = 0; nd < 4; ++nd)
#pragma unroll
      for (int mi = 0; mi < 2; ++mi) po[nd][mi] = (f32x4){0.f,0.f,0.f,0.f};
    ls[0] = (f32x4){0.f,0.f,0.f,0.f}; ls[1] = (f32x4){0.f,0.f,0.f,0.f};
    mrun[0] = mrun[1] = -1e30f;

    const int nkt = (q0 + 128) >> 6;    // = 2(qt+1), always >= 2

    // prologue: tile0 -> buf0, tile1 -> buf1; wait tile0 only (vmcnt(4))
#pragma unroll
    for (int j = 0; j < 2; ++j) {
      gld_lds16(srcK[j], smem + dstP2[j]);
      gld_lds16(srcV[j], smem + 8192 + dstP2[j]);
    }
#pragma unroll
    for (int j = 0; j < 2; ++j) {
      gld_lds16(srcK[j] + (size_t)64*128, smem + 16384 + dstP2[j]);
      gld_lds16(srcV[j] + (size_t)64*2,   smem + 16384 + 8192 + dstP2[j]);
    }
    asm volatile("s_waitcnt vmcnt(4)" ::: "memory");
    __builtin_amdgcn_s_barrier();
    __builtin_amdgcn_sched_barrier(0);

    int rd = 0;                          // buffer index = it % 3
    for (int it = 0; it < nkt; ++it) {
      const int kv0 = it * 64;
      const int cur = rd * 16384;

      // stage tile it+2 into buf[(it+2)%3]
      if (it + 2 < nkt) {
        int wi = rd + 2; if (wi >= 3) wi -= 3;
        const int wb = wi * 16384;
        const size_t ko = (size_t)(kv0 + 128) * 128;
        const size_t vo = (size_t)(kv0 + 128) * 2;
#pragma unroll
        for (int j = 0; j < 2; ++j) {
          gld_lds16(srcK[j] + ko, smem + wb + dstP2[j]);
          gld_lds16(srcV[j] + vo, smem + wb + 8192 + dstP2[j]);
        }
      }

      if (kv0 < q0w + 32) {
        f32x4 st[4][2];
#pragma unroll
        for (int ni = 0; ni < 4; ++ni)
#pragma unroll
          for (int mi = 0; mi < 2; ++mi) st[ni][mi] = (f32x4){0.f,0.f,0.f,0.f};
        __builtin_amdgcn_s_setprio(1);
#pragma unroll
        for (int kk = 0; kk < 2; ++kk) {
          bf16x8 bk[4];
#pragma unroll
          for (int ni = 0; ni < 4; ++ni) {
            int kn = ni*16 + c;
            int Lb = kn*128 + (kk*32 + g*8)*2;
            bk[ni] = *(const bf16x8*)(smem + cur + (Lb ^ ((kn & 7) << 4)));
          }
#pragma unroll
          for (int ni = 0; ni < 4; ++ni)
#pragma unroll
            for (int mi = 0; mi < 2; ++mi)
              st[ni][mi] = __builtin_amdgcn_mfma_f32_16x16x32_bf16(bk[ni], aq[mi][kk], st[ni][mi], 0, 0, 0);
        }
        __builtin_amdgcn_s_setprio(0);

        if (kv0 + 64 > q0w) {
#pragma unroll
          for (int ni = 0; ni < 4; ++ni)
#pragma unroll
            for (int r = 0; r < 4; ++r) {
              int kvv = kv0 + ni*16 + g*4 + r;
#pragma unroll
              for (int mi = 0; mi < 2; ++mi) {
                int qq = q0w + mi*16 + c;
                if (kvv > qq) st[ni][mi][r] = -1e30f;
              }
            }
        }

        // ---- online softmax: tree max (depth 4) + defer-max; sum via MFMA (c)
#pragma unroll
        for (int mi = 0; mi < 2; ++mi) {
          float mn[4];
#pragma unroll
          for (int ni = 0; ni < 4; ++ni)
            mn[ni] = fmaxf(fmaxf(st[ni][mi][0], st[ni][mi][1]),
                           fmaxf(st[ni][mi][2], st[ni][mi][3]));
          float mt = fmaxf(fmaxf(mn[0], mn[1]), fmaxf(mn[2], mn[3]));
          mt = fmaxf(mt, __shfl_xor(mt, 16));
          mt = fmaxf(mt, __shfl_xor(mt, 32));
          float m_use = mrun[mi];
          if (__any(mt > m_use + 8.f)) {
            float mnew = fmaxf(m_use, mt);
            float alpha = exp2_fast(m_use - mnew);
            mrun[mi] = mnew;
            m_use = mnew;
#pragma unroll
            for (int r = 0; r < 4; ++r) ls[mi][r] *= alpha;
#pragma unroll
            for (int nd = 0; nd < 4; ++nd)
#pragma unroll
              for (int r = 0; r < 4; ++r) po[nd][mi][r] *= alpha;
          }
#pragma unroll
          for (int ni = 0; ni < 4; ++ni)
#pragma unroll
            for (int r = 0; r < 4; ++r)
              st[ni][mi][r] = exp2_fast(st[ni][mi][r] - m_use);
        }

        // ---- P^T -> LDS (packed pairs, b64 swizzled stores, wave-private)
#pragma unroll
        for (int mi = 0; mi < 2; ++mi) {
          const int row = mi*16 + c;
          const int sw = (row & 7) << 4;
          const int rb = pbase + row*128;
#pragma unroll
          for (int ni = 0; ni < 4; ++ni) {
            unsigned u0, u1;
            asm("v_cvt_pk_bf16_f32 %0, %1, %2" : "=v"(u0) : "v"(st[ni][mi][0]), "v"(st[ni][mi][1]));
            asm("v_cvt_pk_bf16_f32 %0, %1, %2" : "=v"(u1) : "v"(st[ni][mi][2]), "v"(st[ni][mi][3]));
            int Lb = (ni*16 + g*4) * 2;
            uint2 uu; uu.x = u0; uu.y = u1;
            *(uint2*)(smem + rb + (Lb ^ sw)) = uu;
          }
        }

        __builtin_amdgcn_s_setprio(1);
#pragma unroll
        for (int kk = 0; kk < 2; ++kk) {
          bf16x8 pb[2];
#pragma unroll
          for (int mi = 0; mi < 2; ++mi) {
            int pr = mi*16 + c;
            int Lb = pr*128 + (kk*32 + g*8)*2;
            pb[mi] = *(const bf16x8*)(smem + pbase + (Lb ^ ((pr & 7) << 4)));
          }
          // (c) row-sum via ones-MFMA (matrix pipe is idle; kills serial add chain)
#pragma unroll
          for (int mi = 0; mi < 2; ++mi)
            ls[mi] = __builtin_amdgcn_mfma_f32_16x16x32_bf16(vones, pb[mi], ls[mi], 0, 0, 0);
          bf16x8 bv[4];
#pragma unroll
          for (int nd = 0; nd < 4; ++nd) {
            int vr = nd*16 + c;
            int Lb = vr*128 + (kk*32 + g*8)*2;
            bv[nd] = *(const bf16x8*)(smem + cur + 8192 + (Lb ^ ((vr & 7) << 4)));
          }
#pragma unroll
          for (int nd = 0; nd < 4; ++nd)
#pragma unroll
            for (int mi = 0; mi < 2; ++mi)
              po[nd][mi] = __builtin_amdgcn_mfma_f32_16x16x32_bf16(bv[nd], pb[mi], po[nd][mi], 0, 0, 0);
        }
        __builtin_amdgcn_s_setprio(0);
      }

      // gate: validate buf[(it+1)%3] for next iter; keep this iter's stages in flight
      if (it + 1 < nkt) {
        if (it + 2 < nkt) { asm volatile("s_waitcnt vmcnt(4)" ::: "memory"); }
        else              { asm volatile("s_waitcnt vmcnt(0)" ::: "memory"); }
      }
      __builtin_amdgcn_s_barrier();
      __builtin_amdgcn_sched_barrier(0);
      rd = (rd == 2) ? 0 : rd + 1;
    }

    // ---- normalize + store; ls[mi][0] = full 64-kv sum for q col c (all lanes)
#pragma unroll
    for (int mi = 0; mi < 2; ++mi) {
      float inv = 1.f / ls[mi][0];
      int t = q0w + mi*16 + c;
#pragma unroll
      for (int nd = 0; nd < 4; ++nd) {
        ushort4 o;
        o.x = f2bf(po[nd][mi][0] * inv);
        o.y = f2bf(po[nd][mi][1] * inv);
        o.z = f2bf(po[nd][mi][2] * inv);
        o.w = f2bf(po[nd][mi][3] * inv);
        *(ushort4*)(yb + ((size_t)b*T_ + t)*C_ + h*64 + nd*16 + g*4) = o;
      }
    }
  }
}

// ---------------------------------------------------------------- launcher
extern "C" void kernel_launch(void* const* d_in, const int* in_sizes, int n_in,
                              void* d_out, int out_size, void* d_ws, size_t ws_size,
                              hipStream_t stream)
{
  const float* x  = (const float*)d_in[0];
  const float* Wq = (const float*)d_in[1];
  const float* Wk = (const float*)d_in[2];
  const float* Wv = (const float*)d_in[3];
  const float* Wp = (const float*)d_in[4];
  const int*   sp = (const int*)d_in[5];
  float* out = (float*)d_out;

  char* ws = (char*)d_ws;
  unsigned short* xb   = (unsigned short*)(ws);                  // 16 MB
  unsigned short* wcat = (unsigned short*)(ws + 16777216);       // 6 MB [Wq;Wk;Wv]
  unsigned short* wpb  = (unsigned short*)(ws + 23068672);       // 2 MB
  unsigned short* qb   = (unsigned short*)(ws + 25165824);       // 16 MB (B,H,T,D)
  unsigned short* kb   = (unsigned short*)(ws + 41943040);       // 16 MB (B,H,T,D)
  unsigned short* vt   = (unsigned short*)(ws + 58720256);       // 16 MB (B,H,D,T)
  unsigned short* yb   = (unsigned short*)(ws + 75497472);       // 16 MB (B*T, C)
  float* cosT = (float*)(ws + 92274688);                         // 512 KB [T][D]
  float* sinT = (float*)(ws + 92798976);                         // 512 KB [T][D]

  k_convert<<<dim3(2048), dim3(256), 0, stream>>>(x, Wq, Wk, Wv, Wp, xb, wcat, wpb);
  k_rope_tab<<<dim3(512), dim3(256), 0, stream>>>(sp, cosT, sinT);
  k_gemm256<<<dim3(32, 12), dim3(512), 0, stream>>>(xb, wcat, qb, kb, vt, cosT, sinT);
  k_attn<<<dim3(64, 8), dim3(256), 0, stream>>>(qb, kb, vt, yb);
  k_gemm<1><<<dim3(64, 8), dim3(256), 0, stream>>>(yb, wpb, nullptr, nullptr, nullptr, nullptr, nullptr, out);
}

// Round 14
// 173.357 us; speedup vs baseline: 1.0745x; 1.0745x over previous
//
#include <hip/hip_runtime.h>
#include <hip/hip_bf16.h>
#include <stdint.h>

// Problem constants
#define B_  4
#define T_  2048
#define C_  1024
#define H_  16
#define D_  64
#define BT  (B_*T_)     // 8192
#define KDIM 1024

typedef __attribute__((ext_vector_type(8))) short bf16x8;
typedef __attribute__((ext_vector_type(4))) float f32x4;

__device__ __forceinline__ unsigned short f2bf(float f) {
  union { float f; unsigned u; } v; v.f = f;
  unsigned r = v.u + 0x7FFFu + ((v.u >> 16) & 1u);   // RNE
  return (unsigned short)(r >> 16);
}

__device__ __forceinline__ float exp2_fast(float x) {   // raw v_exp_f32 (2^x)
  float r;
  asm("v_exp_f32 %0, %1" : "=v"(r) : "v"(x));
  return r;
}

// async global->LDS, 16B per lane. dest must be wave-uniform base + lane*16 (linear).
__device__ __forceinline__ void gld_lds16(const void* g, void* l) {
  __builtin_amdgcn_global_load_lds(
      (__attribute__((address_space(1))) unsigned int*)(uintptr_t)g,
      (__attribute__((address_space(3))) unsigned int*)(unsigned)(uintptr_t)l,
      16, 0, 0);
}

// ---------------------------------------------------------------- prep kernels
__global__ __launch_bounds__(256) void k_convert(
    const float* __restrict__ x,  const float* __restrict__ wq,
    const float* __restrict__ wk, const float* __restrict__ wv,
    const float* __restrict__ wp,
    unsigned short* __restrict__ xb, unsigned short* __restrict__ wcat,
    unsigned short* __restrict__ wpb)
{
  const int NX = BT*C_/4;       // 2097152 float4s of x
  const int NW = C_*C_/4;       // 262144 per W
  const int TOT = NX + 4*NW;
  for (int i = blockIdx.x*blockDim.x + threadIdx.x; i < TOT; i += gridDim.x*blockDim.x) {
    const float4* src; unsigned short* dst; int idx;
    if (i < NX)                { src = (const float4*)x;  dst = xb;            idx = i; }
    else {
      int j = i - NX;
      if (j < NW)              { src = (const float4*)wq; dst = wcat;          idx = j; }
      else if (j < 2*NW)       { src = (const float4*)wk; dst = wcat + C_*C_;  idx = j - NW; }
      else if (j < 3*NW)       { src = (const float4*)wv; dst = wcat + 2*C_*C_;idx = j - 2*NW; }
      else                     { src = (const float4*)wp; dst = wpb;           idx = j - 3*NW; }
    }
    float4 v = src[idx];
    ushort4 o; o.x = f2bf(v.x); o.y = f2bf(v.y); o.z = f2bf(v.z); o.w = f2bf(v.w);
    *(ushort4*)(dst + (size_t)idx*4) = o;
  }
}

// RoPE tables [T][D] (coalesced epilogue loads).
__global__ __launch_bounds__(256) void k_rope_tab(
    const int* __restrict__ start_pos, float* __restrict__ cosT, float* __restrict__ sinT)
{
  int i = blockIdx.x*blockDim.x + threadIdx.x;   // [0, T_*64)
  if (i >= T_*D_) return;
  int t = i >> 6, j = i & 63;
  float inv = exp2f(-(float)(j & 31) * (13.287712379549449f / 32.0f));
  float ang = (float)(t + start_pos[0]) * inv;
  cosT[i] = cosf(ang);
  sinT[i] = sinf(ang);
}

// ---------------------------------------------------------------- 256x256 8-wave GEMM, counted-vmcnt schedule
// (unchanged from R10/R11/R12)
__global__ __launch_bounds__(512, 2) void k_gemm256(
    const unsigned short* __restrict__ A, const unsigned short* __restrict__ Bw,
    unsigned short* __restrict__ qb, unsigned short* __restrict__ kb,
    unsigned short* __restrict__ vt,
    const float* __restrict__ cosT, const float* __restrict__ sinT)
{
  __shared__ __attribute__((aligned(16))) char smem[131072];
  const int tid = threadIdx.x, l = tid & 63, w = tid >> 6;
  const int g = l >> 4, c = l & 15;
  const int m0 = blockIdx.x * 256, n0 = blockIdx.y * 256;
  const int wr = w >> 2, wc = w & 3;
  const char* gA = (const char*)A;
  const char* gB = (const char*)Bw;

  int dstU[2]; size_t aoff[2], boff[2];
#pragma unroll
  for (int j = 0; j < 2; ++j) {
    int P = j*8192 + tid*16;
    int p = P >> 7;
    int inner = (P & 127) ^ ((p & 7) << 4);
    int row = (p << 1) | (inner >> 6);
    int kc = (inner & 63) >> 1;
    dstU[j] = P;
    aoff[j] = ((size_t)(m0 + row) * KDIM + kc) * 2;
    boff[j] = ((size_t)(n0 + row) * KDIM + kc) * 2;
  }

  const int swzo = ((((c & 1) << 6) | (g << 4)) ^ (((c >> 1) & 7) << 4));
  const int aB = (wr*64 + (c >> 1)) * 128 + swzo;
  const int bB = 32768 + (wc*32 + (c >> 1)) * 128 + swzo;

  f32x4 acc[8][4];
#pragma unroll
  for (int i = 0; i < 8; ++i)
#pragma unroll
    for (int j = 0; j < 4; ++j) acc[i][j] = (f32x4){0.f,0.f,0.f,0.f};

#pragma unroll
  for (int j = 0; j < 2; ++j) gld_lds16(gA + aoff[j],      smem +     0 + dstU[j]);
#pragma unroll
  for (int j = 0; j < 2; ++j) gld_lds16(gB + boff[j],      smem + 32768 + dstU[j]);
#pragma unroll
  for (int j = 0; j < 2; ++j) gld_lds16(gA + aoff[j] + 64, smem + 16384 + dstU[j]);
#pragma unroll
  for (int j = 0; j < 2; ++j) gld_lds16(gB + boff[j] + 64, smem + 49152 + dstU[j]);
  asm volatile("s_waitcnt vmcnt(4)" ::: "memory");
  __builtin_amdgcn_s_barrier();

#define MFMA16(MB)                                                               \
    __builtin_amdgcn_s_setprio(1);                                               \
    _Pragma("unroll")                                                            \
    for (int i2 = 0; i2 < 4; ++i2)                                               \
      _Pragma("unroll")                                                          \
      for (int ni = 0; ni < 4; ++ni)                                             \
        acc[(MB)+i2][ni] = __builtin_amdgcn_mfma_f32_16x16x32_bf16(              \
            af[i2], bk[ni], acc[(MB)+i2][ni], 0, 0, 0);                          \
    __builtin_amdgcn_s_setprio(0);

#define PRE_MFMA                                                                 \
    __builtin_amdgcn_s_barrier();                                                \
    asm volatile("s_waitcnt lgkmcnt(0)" ::: "memory");                           \
    __builtin_amdgcn_sched_barrier(0);

  bf16x8 af[4], bk[4];

#pragma unroll 2
  for (int t = 0; t < 15; ++t) {
    const int par = (t & 1) << 16;
    const int nxt = par ^ 65536;
    const size_t ko = (size_t)(t + 1) * 128;

#pragma unroll
    for (int i2 = 0; i2 < 4; ++i2) af[i2] = *(const bf16x8*)(smem + par + aB + i2*1024);
#pragma unroll
    for (int ni = 0; ni < 4; ++ni) bk[ni] = *(const bf16x8*)(smem + par + bB + ni*1024);
#pragma unroll
    for (int j = 0; j < 2; ++j) gld_lds16(gA + aoff[j] + ko, smem + nxt + dstU[j]);
    PRE_MFMA
    MFMA16(0)
    __builtin_amdgcn_s_barrier();

#pragma unroll
    for (int i2 = 0; i2 < 4; ++i2) af[i2] = *(const bf16x8*)(smem + par + aB + (4+i2)*1024);
#pragma unroll
    for (int j = 0; j < 2; ++j) gld_lds16(gB + boff[j] + ko, smem + nxt + 32768 + dstU[j]);
    PRE_MFMA
    MFMA16(4)
    asm volatile("s_waitcnt vmcnt(4)" ::: "memory");
    __builtin_amdgcn_s_barrier();

#pragma unroll
    for (int i2 = 0; i2 < 4; ++i2) af[i2] = *(const bf16x8*)(smem + par + 16384 + aB + i2*1024);
#pragma unroll
    for (int ni = 0; ni < 4; ++ni) bk[ni] = *(const bf16x8*)(smem + par + 16384 + bB + ni*1024);
#pragma unroll
    for (int j = 0; j < 2; ++j) gld_lds16(gA + aoff[j] + ko + 64, smem + nxt + 16384 + dstU[j]);
    PRE_MFMA
    MFMA16(0)
    __builtin_amdgcn_s_barrier();

#pragma unroll
    for (int i2 = 0; i2 < 4; ++i2) af[i2] = *(const bf16x8*)(smem + par + 16384 + aB + (4+i2)*1024);
#pragma unroll
    for (int j = 0; j < 2; ++j) gld_lds16(gB + boff[j] + ko + 64, smem + nxt + 49152 + dstU[j]);
    PRE_MFMA
    MFMA16(4)
    asm volatile("s_waitcnt vmcnt(4)" ::: "memory");
    __builtin_amdgcn_s_barrier();
  }

  {
    const int par = 65536;
#pragma unroll
    for (int i2 = 0; i2 < 4; ++i2) af[i2] = *(const bf16x8*)(smem + par + aB + i2*1024);
#pragma unroll
    for (int ni = 0; ni < 4; ++ni) bk[ni] = *(const bf16x8*)(smem + par + bB + ni*1024);
    PRE_MFMA
    MFMA16(0)
    __builtin_amdgcn_s_barrier();
#pragma unroll
    for (int i2 = 0; i2 < 4; ++i2) af[i2] = *(const bf16x8*)(smem + par + aB + (4+i2)*1024);
    PRE_MFMA
    MFMA16(4)
    asm volatile("s_waitcnt vmcnt(0)" ::: "memory");
    __builtin_amdgcn_s_barrier();
#pragma unroll
    for (int i2 = 0; i2 < 4; ++i2) af[i2] = *(const bf16x8*)(smem + par + 16384 + aB + i2*1024);
#pragma unroll
    for (int ni = 0; ni < 4; ++ni) bk[ni] = *(const bf16x8*)(smem + par + 16384 + bB + ni*1024);
    PRE_MFMA
    MFMA16(0)
    __builtin_amdgcn_s_barrier();
#pragma unroll
    for (int i2 = 0; i2 < 4; ++i2) af[i2] = *(const bf16x8*)(smem + par + 16384 + aB + (4+i2)*1024);
    PRE_MFMA
    MFMA16(4)
  }
#undef MFMA16
#undef PRE_MFMA

  // epilogue: fused RoPE; C layout: col = lane&15, row = g*4 + r
#pragma unroll
  for (int mi = 0; mi < 8; ++mi) {
#pragma unroll
    for (int ni = 0; ni < 4; ++ni) {
      const int mrow0 = m0 + wr*128 + mi*16 + g*4;
      const int ncol  = n0 + wc*64 + ni*16 + c;
      const int which = ncol >> 10;          // 0=q 1=k 2=v (block-uniform)
      const int d = ncol & 1023, h = d >> 6, dd = d & 63;
      const int b = mrow0 >> 11, t0 = mrow0 & 2047;
      if (which == 2) {
        ushort4 o;
        o.x = f2bf(acc[mi][ni][0]); o.y = f2bf(acc[mi][ni][1]);
        o.z = f2bf(acc[mi][ni][2]); o.w = f2bf(acc[mi][ni][3]);
        *(ushort4*)(vt + ((size_t)((b*H_ + h)*D_ + dd))*T_ + t0) = o;
      } else {
#pragma unroll
        for (int r = 0; r < 4; ++r) {
          float val = acc[mi][ni][r];
          float partner = __shfl_xor(val, 1);          // value at dd^1 (lane^1)
          float rot = (dd & 1) ? partner : -partner;   // interleaved rotate_half
          float cv = cosT[(t0 + r)*64 + dd], sv = sinT[(t0 + r)*64 + dd];
          float o = val*cv + rot*sv;
          size_t oidx = (((size_t)(b*H_ + h))*T_ + (t0 + r))*D_ + dd;
          if (which == 0) qb[oidx] = f2bf(o * 0.180336879f);
          else            kb[oidx] = f2bf(o);
        }
      }
    }
  }
}

// ---------------------------------------------------------------- GEMM (NT, bf16), 128x128
// (unchanged proven template; output projection, EPI=1)
template<int EPI>
__global__ __launch_bounds__(256) void k_gemm(
    const unsigned short* __restrict__ A, const unsigned short* __restrict__ Bw,
    unsigned short* __restrict__ qb, unsigned short* __restrict__ kb,
    unsigned short* __restrict__ vt,
    const float* __restrict__ cosT, const float* __restrict__ sinT,
    float* __restrict__ outF)
{
  __shared__ __attribute__((aligned(16))) char smem[32768];  // A:16K B:16K
  const int tid = threadIdx.x, l = tid & 63, w = tid >> 6;
  const int g = l >> 4, c = l & 15;
  const int m0 = blockIdx.x * 128, n0 = blockIdx.y * 128;
  const int wr = w >> 1, wc = w & 1;

  const char* srcA[4]; const char* srcB[4]; int dstP[4];
#pragma unroll
  for (int j = 0; j < 4; ++j) {
    int P = w*4096 + j*1024 + l*16;
    int row = P >> 7;
    int Lb = P ^ ((row & 7) << 4);
    int col = (Lb & 127) >> 1;
    dstP[j] = P;
    srcA[j] = (const char*)A  + ((size_t)(m0 + row) * KDIM + col) * 2;
    srcB[j] = (const char*)Bw + ((size_t)(n0 + row) * KDIM + col) * 2;
  }

  f32x4 acc[4][4];
#pragma unroll
  for (int i = 0; i < 4; ++i)
#pragma unroll
    for (int j = 0; j < 4; ++j) acc[i][j] = (f32x4){0.f,0.f,0.f,0.f};

  for (int kt = 0; kt < KDIM; kt += 64) {
#pragma unroll
    for (int j = 0; j < 4; ++j) {
      gld_lds16(srcA[j] + kt*2, smem + dstP[j]);
      gld_lds16(srcB[j] + kt*2, smem + 16384 + dstP[j]);
    }
    __syncthreads();
#pragma unroll
    for (int kk = 0; kk < 2; ++kk) {
      bf16x8 af[4], bw4[4];
#pragma unroll
      for (int mi = 0; mi < 4; ++mi) {
        int row = wr*64 + mi*16 + c;
        int Lb = row*128 + (kk*32 + g*8)*2;
        af[mi] = *(const bf16x8*)(smem + (Lb ^ ((row & 7) << 4)));
      }
#pragma unroll
      for (int ni = 0; ni < 4; ++ni) {
        int row = wc*64 + ni*16 + c;
        int Lb = row*128 + (kk*32 + g*8)*2;
        bw4[ni] = *(const bf16x8*)(smem + 16384 + (Lb ^ ((row & 7) << 4)));
      }
#pragma unroll
      for (int mi = 0; mi < 4; ++mi)
#pragma unroll
        for (int ni = 0; ni < 4; ++ni)
          acc[mi][ni] = __builtin_amdgcn_mfma_f32_16x16x32_bf16(af[mi], bw4[ni], acc[mi][ni], 0, 0, 0);
    }
    __syncthreads();
  }

#pragma unroll
  for (int mi = 0; mi < 4; ++mi) {
#pragma unroll
    for (int ni = 0; ni < 4; ++ni) {
      const int mrow0 = m0 + wr*64 + mi*16 + g*4;
      const int ncol  = n0 + wc*64 + ni*16 + c;
      if (EPI == 1) {
#pragma unroll
        for (int r = 0; r < 4; ++r)
          outF[(size_t)(mrow0 + r) * 1024 + ncol] = acc[mi][ni][r];
      } else {
        const int which = ncol >> 10;
        const int d = ncol & 1023, h = d >> 6, dd = d & 63;
        const int b = mrow0 >> 11, t0 = mrow0 & 2047;
        if (which == 2) {
          ushort4 o;
          o.x = f2bf(acc[mi][ni][0]); o.y = f2bf(acc[mi][ni][1]);
          o.z = f2bf(acc[mi][ni][2]); o.w = f2bf(acc[mi][ni][3]);
          *(ushort4*)(vt + ((size_t)((b*H_ + h)*D_ + dd))*T_ + t0) = o;
        } else {
#pragma unroll
          for (int r = 0; r < 4; ++r) {
            float val = acc[mi][ni][r];
            float partner = __shfl_xor(val, 1);
            float rot = (dd & 1) ? partner : -partner;
            float cv = cosT[(t0 + r)*64 + dd], sv = sinT[(t0 + r)*64 + dd];
            float o = val*cv + rot*sv;
            size_t oidx = (((size_t)(b*H_ + h))*T_ + (t0 + r))*D_ + dd;
            if (which == 0) qb[oidx] = f2bf(o * 0.180336879f);
            else            kb[oidx] = f2bf(o);
          }
        }
      }
    }
  }
}

// ---------------------------------------------------------------- flash attention
// R12 structure re-partitioned for occupancy: 8 waves x 16 q-rows (512 thr).
// Same 128-row q-tile pairing, same XCD-locality grid (x=bh), same 3-deep KV
// buffers with counted vmcnt (loads/tile/wave = 2 -> gate = vmcnt(2)).
// All 8 waves share the staged KV stream (1 K-load + 1 V-load per wave per tile).
// Per-wave P tile = [16 q][64 kv] bf16 = 2 KB; LDS = 48K KV + 16K P = 64 KB
// -> 2 blocks/CU x 8 waves = 16 waves/CU = 4 waves/SIMD (2x R12's TLP).
__global__ __launch_bounds__(512) void k_attn(
    const unsigned short* __restrict__ qb, const unsigned short* __restrict__ kb,
    const unsigned short* __restrict__ vt, unsigned short* __restrict__ yb)
{
  __shared__ __attribute__((aligned(16))) char smem[65536]; // 3x(K8K+V8K) + P:16K
  const int tid = threadIdx.x, l = tid & 63, w = tid >> 6;  // w in 0..7
  const int g = l >> 4, c = l & 15;
  const int bh = blockIdx.x;                 // x = bh -> XCD locality (R12)
  const int pidx = blockIdx.y;               // pair index 0..7
  const size_t bhO = (size_t)bh * T_ * D_;
  const int pbase = 49152 + w*2048;          // per-wave 2 KB P region
  const int b = bh >> 4, h = bh & 15;

  bf16x8 vones;
#pragma unroll
  for (int i = 0; i < 8; ++i) vones[i] = (short)0x3F80;   // bf16 1.0

  // staging descriptors: 1 x 16B per thread per buffer (8 waves cover 8 KB)
  const char* srcK; const char* srcV; int dstP2;
  {
    int P = w*1024 + l*16;                 // [0, 8192)
    int row = P >> 7;
    int Lb = P ^ ((row & 7) << 4);
    int col = (Lb & 127) >> 1;
    dstP2 = P;
    srcK = (const char*)(kb + bhO) + ((size_t)row*D_ + col)*2;   // + kv0*128B
    srcV = (const char*)(vt + bhO) + ((size_t)row*T_ + col)*2;   // + kv0*2B
  }

  for (int half = 0; half < 2; ++half) {
    const int qt = half ? pidx : (15 - pidx);
    const int q0 = qt * 128;
    const int q0w = q0 + w*16;             // this wave's 16 q rows

    // Q fragments (q pre-scaled by log2e/8): row = q0w + c
    bf16x8 aq[2];
#pragma unroll
    for (int kc = 0; kc < 2; ++kc)
      aq[kc] = *(const bf16x8*)(qb + bhO + (size_t)(q0w + c)*D_ + kc*32 + g*8);

    f32x4 po[4];                  // O^T: [nd], lane: d = nd*16+g*4+r, q = c
    f32x4 ls;                     // MFMA row-sum accumulator (all regs = full sum)
    float mrun = -1e30f;
#pragma unroll
    for (int nd = 0; nd < 4; ++nd) po[nd] = (f32x4){0.f,0.f,0.f,0.f};
    ls = (f32x4){0.f,0.f,0.f,0.f};

    const int nkt = (q0 + 128) >> 6;       // = 2(qt+1), always >= 2

    // prologue: tile0 -> buf0, tile1 -> buf1; drain tile0 (2 loads) -> vmcnt(2)
    gld_lds16(srcK, smem + dstP2);
    gld_lds16(srcV, smem + 8192 + dstP2);
    gld_lds16(srcK + (size_t)64*128, smem + 16384 + dstP2);
    gld_lds16(srcV + (size_t)64*2,   smem + 16384 + 8192 + dstP2);
    asm volatile("s_waitcnt vmcnt(2)" ::: "memory");
    __builtin_amdgcn_s_barrier();
    __builtin_amdgcn_sched_barrier(0);

    int rd = 0;                            // buffer index = it % 3
    for (int it = 0; it < nkt; ++it) {
      const int kv0 = it * 64;
      const int cur = rd * 16384;

      // stage tile it+2 into buf[(it+2)%3]
      if (it + 2 < nkt) {
        int wi = rd + 2; if (wi >= 3) wi -= 3;
        const int wb = wi * 16384;
        gld_lds16(srcK + (size_t)(kv0 + 128) * 128, smem + wb + dstP2);
        gld_lds16(srcV + (size_t)(kv0 + 128) * 2,   smem + wb + 8192 + dstP2);
      }

      if (kv0 < q0w + 16) {               // wave has >=1 unmasked element
        // ---- S^T = K Q^T  (64 kv x 16 q per wave)
        f32x4 st[4];
#pragma unroll
        for (int ni = 0; ni < 4; ++ni) st[ni] = (f32x4){0.f,0.f,0.f,0.f};
        __builtin_amdgcn_s_setprio(1);
#pragma unroll
        for (int kk = 0; kk < 2; ++kk) {
          bf16x8 bk[4];
#pragma unroll
          for (int ni = 0; ni < 4; ++ni) {
            int kn = ni*16 + c;
            int Lb = kn*128 + (kk*32 + g*8)*2;
            bk[ni] = *(const bf16x8*)(smem + cur + (Lb ^ ((kn & 7) << 4)));
          }
#pragma unroll
          for (int ni = 0; ni < 4; ++ni)
            st[ni] = __builtin_amdgcn_mfma_f32_16x16x32_bf16(bk[ni], aq[kk], st[ni], 0, 0, 0);
        }
        __builtin_amdgcn_s_setprio(0);

        // ---- causal mask (partial tiles only)
        if (kv0 + 64 > q0w) {
          const int qq = q0w + c;
#pragma unroll
          for (int ni = 0; ni < 4; ++ni)
#pragma unroll
            for (int r = 0; r < 4; ++r) {
              int kvv = kv0 + ni*16 + g*4 + r;
              if (kvv > qq) st[ni][r] = -1e30f;
            }
        }

        // ---- online softmax: tree max + defer-max; sum via ones-MFMA
        {
          float mn[4];
#pragma unroll
          for (int ni = 0; ni < 4; ++ni)
            mn[ni] = fmaxf(fmaxf(st[ni][0], st[ni][1]), fmaxf(st[ni][2], st[ni][3]));
          float mt = fmaxf(fmaxf(mn[0], mn[1]), fmaxf(mn[2], mn[3]));
          mt = fmaxf(mt, __shfl_xor(mt, 16));
          mt = fmaxf(mt, __shfl_xor(mt, 32));
          float m_use = mrun;
          if (__any(mt > m_use + 8.f)) {
            float mnew = fmaxf(m_use, mt);
            float alpha = exp2_fast(m_use - mnew);
            mrun = mnew;
            m_use = mnew;
#pragma unroll
            for (int r = 0; r < 4; ++r) ls[r] *= alpha;
#pragma unroll
            for (int nd = 0; nd < 4; ++nd)
#pragma unroll
              for (int r = 0; r < 4; ++r) po[nd][r] *= alpha;
          }
#pragma unroll
          for (int ni = 0; ni < 4; ++ni)
#pragma unroll
            for (int r = 0; r < 4; ++r)
              st[ni][r] = exp2_fast(st[ni][r] - m_use);
        }

        // ---- P^T -> LDS (wave-private 2 KB; row = q = c, col = kv)
        {
          const int row = c;
          const int sw = (row & 7) << 4;
          const int rb = pbase + row*128;
#pragma unroll
          for (int ni = 0; ni < 4; ++ni) {
            unsigned u0, u1;
            asm("v_cvt_pk_bf16_f32 %0, %1, %2" : "=v"(u0) : "v"(st[ni][0]), "v"(st[ni][1]));
            asm("v_cvt_pk_bf16_f32 %0, %1, %2" : "=v"(u1) : "v"(st[ni][2]), "v"(st[ni][3]));
            int Lb = (ni*16 + g*4) * 2;      // 8B-aligned; sw flips bits 4-6 only
            uint2 uu; uu.x = u0; uu.y = u1;
            *(uint2*)(smem + rb + (Lb ^ sw)) = uu;
          }
        }

        // ---- O^T += Vt * P^T ; row-sum via ones-MFMA
        __builtin_amdgcn_s_setprio(1);
#pragma unroll
        for (int kk = 0; kk < 2; ++kk) {
          bf16x8 pb;
          {
            int pr = c;
            int Lb = pr*128 + (kk*32 + g*8)*2;
            pb = *(const bf16x8*)(smem + pbase + (Lb ^ ((pr & 7) << 4)));
          }
          ls = __builtin_amdgcn_mfma_f32_16x16x32_bf16(vones, pb, ls, 0, 0, 0);
          bf16x8 bv[4];
#pragma unroll
          for (int nd = 0; nd < 4; ++nd) {
            int vr = nd*16 + c;
            int Lb = vr*128 + (kk*32 + g*8)*2;
            bv[nd] = *(const bf16x8*)(smem + cur + 8192 + (Lb ^ ((vr & 7) << 4)));
          }
#pragma unroll
          for (int nd = 0; nd < 4; ++nd)
            po[nd] = __builtin_amdgcn_mfma_f32_16x16x32_bf16(bv[nd], pb, po[nd], 0, 0, 0);
        }
        __builtin_amdgcn_s_setprio(0);
      }

      // gate: validate buf[(it+1)%3]; keep this iter's stages in flight
      if (it + 1 < nkt) {
        if (it + 2 < nkt) { asm volatile("s_waitcnt vmcnt(2)" ::: "memory"); }
        else              { asm volatile("s_waitcnt vmcnt(0)" ::: "memory"); }
      }
      __builtin_amdgcn_s_barrier();
      __builtin_amdgcn_sched_barrier(0);
      rd = (rd == 2) ? 0 : rd + 1;
    }

    // ---- normalize + store; ls[0] = full 64-kv sum for q col c (all lanes)
    {
      float inv = 1.f / ls[0];
      int t = q0w + c;
#pragma unroll
      for (int nd = 0; nd < 4; ++nd) {
        ushort4 o;
        o.x = f2bf(po[nd][0] * inv);
        o.y = f2bf(po[nd][1] * inv);
        o.z = f2bf(po[nd][2] * inv);
        o.w = f2bf(po[nd][3] * inv);
        *(ushort4*)(yb + ((size_t)b*T_ + t)*C_ + h*64 + nd*16 + g*4) = o;
      }
    }
  }
}

// ---------------------------------------------------------------- launcher
extern "C" void kernel_launch(void* const* d_in, const int* in_sizes, int n_in,
                              void* d_out, int out_size, void* d_ws, size_t ws_size,
                              hipStream_t stream)
{
  const float* x  = (const float*)d_in[0];
  const float* Wq = (const float*)d_in[1];
  const float* Wk = (const float*)d_in[2];
  const float* Wv = (const float*)d_in[3];
  const float* Wp = (const float*)d_in[4];
  const int*   sp = (const int*)d_in[5];
  float* out = (float*)d_out;

  char* ws = (char*)d_ws;
  unsigned short* xb   = (unsigned short*)(ws);                  // 16 MB
  unsigned short* wcat = (unsigned short*)(ws + 16777216);       // 6 MB [Wq;Wk;Wv]
  unsigned short* wpb  = (unsigned short*)(ws + 23068672);       // 2 MB
  unsigned short* qb   = (unsigned short*)(ws + 25165824);       // 16 MB (B,H,T,D)
  unsigned short* kb   = (unsigned short*)(ws + 41943040);       // 16 MB (B,H,T,D)
  unsigned short* vt   = (unsigned short*)(ws + 58720256);       // 16 MB (B,H,D,T)
  unsigned short* yb   = (unsigned short*)(ws + 75497472);       // 16 MB (B*T, C)
  float* cosT = (float*)(ws + 92274688);                         // 512 KB [T][D]
  float* sinT = (float*)(ws + 92798976);                         // 512 KB [T][D]

  k_convert<<<dim3(2048), dim3(256), 0, stream>>>(x, Wq, Wk, Wv, Wp, xb, wcat, wpb);
  k_rope_tab<<<dim3(512), dim3(256), 0, stream>>>(sp, cosT, sinT);
  k_gemm256<<<dim3(32, 12), dim3(512), 0, stream>>>(xb, wcat, qb, kb, vt, cosT, sinT);
  k_attn<<<dim3(64, 8), dim3(512), 0, stream>>>(qb, kb, vt, yb);
  k_gemm<1><<<dim3(64, 8), dim3(256), 0, stream>>>(yb, wpb, nullptr, nullptr, nullptr, nullptr, nullptr, out);
}

// Round 15
// 168.839 us; speedup vs baseline: 1.1032x; 1.0268x over previous
//
#include <hip/hip_runtime.h>
#include <hip/hip_bf16.h>
#include <stdint.h>

// Problem constants
#define B_  4
#define T_  2048
#define C_  1024
#define H_  16
#define D_  64
#define BT  (B_*T_)     // 8192
#define KDIM 1024

typedef __attribute__((ext_vector_type(8))) short bf16x8;
typedef __attribute__((ext_vector_type(4))) float f32x4;

__device__ __forceinline__ unsigned short f2bf(float f) {
  union { float f; unsigned u; } v; v.f = f;
  unsigned r = v.u + 0x7FFFu + ((v.u >> 16) & 1u);   // RNE
  return (unsigned short)(r >> 16);
}

__device__ __forceinline__ float exp2_fast(float x) {   // raw v_exp_f32 (2^x)
  float r;
  asm("v_exp_f32 %0, %1" : "=v"(r) : "v"(x));
  return r;
}

// async global->LDS, 16B per lane. dest must be wave-uniform base + lane*16 (linear).
__device__ __forceinline__ void gld_lds16(const void* g, void* l) {
  __builtin_amdgcn_global_load_lds(
      (__attribute__((address_space(1))) unsigned int*)(uintptr_t)g,
      (__attribute__((address_space(3))) unsigned int*)(unsigned)(uintptr_t)l,
      16, 0, 0);
}

// ---------------------------------------------------------------- prep kernels
__global__ __launch_bounds__(256) void k_convert(
    const float* __restrict__ x,  const float* __restrict__ wq,
    const float* __restrict__ wk, const float* __restrict__ wv,
    const float* __restrict__ wp,
    unsigned short* __restrict__ xb, unsigned short* __restrict__ wcat,
    unsigned short* __restrict__ wpb)
{
  const int NX = BT*C_/4;       // 2097152 float4s of x
  const int NW = C_*C_/4;       // 262144 per W
  const int TOT = NX + 4*NW;
  for (int i = blockIdx.x*blockDim.x + threadIdx.x; i < TOT; i += gridDim.x*blockDim.x) {
    const float4* src; unsigned short* dst; int idx;
    if (i < NX)                { src = (const float4*)x;  dst = xb;            idx = i; }
    else {
      int j = i - NX;
      if (j < NW)              { src = (const float4*)wq; dst = wcat;          idx = j; }
      else if (j < 2*NW)       { src = (const float4*)wk; dst = wcat + C_*C_;  idx = j - NW; }
      else if (j < 3*NW)       { src = (const float4*)wv; dst = wcat + 2*C_*C_;idx = j - 2*NW; }
      else                     { src = (const float4*)wp; dst = wpb;           idx = j - 3*NW; }
    }
    float4 v = src[idx];
    ushort4 o; o.x = f2bf(v.x); o.y = f2bf(v.y); o.z = f2bf(v.z); o.w = f2bf(v.w);
    *(ushort4*)(dst + (size_t)idx*4) = o;
  }
}

// RoPE tables [T][D] (coalesced epilogue loads).
__global__ __launch_bounds__(256) void k_rope_tab(
    const int* __restrict__ start_pos, float* __restrict__ cosT, float* __restrict__ sinT)
{
  int i = blockIdx.x*blockDim.x + threadIdx.x;   // [0, T_*64)
  if (i >= T_*D_) return;
  int t = i >> 6, j = i & 63;
  float inv = exp2f(-(float)(j & 31) * (13.287712379549449f / 32.0f));
  float ang = (float)(t + start_pos[0]) * inv;
  cosT[i] = cosf(ang);
  sinT[i] = sinf(ang);
}

// ---------------------------------------------------------------- 256x256 8-wave GEMM, barrier-minimal
// BM=BN=256, BK=64, 512 thr / 8 waves (2M x 4N), per-wave C = 128x64 (acc[8][4]).
// LDS 128KB: parity p in {0,1}: [A 32KB | B 32KB]. Unit layout: [256 rows][128B],
// byte = row*128 + (kc*2 ^ ((row&7)<<4))  (proven conflict-free pattern).
// K-loop = 16 tiles, ONE __syncthreads per tile:
//   { sync; stage tile t+1 -> other parity (8 gld_lds); 24 ds_read + 64 MFMA }
// The sync's implicit vmcnt(0) drains loads issued a FULL TILE earlier (~2800cyc)
// -> no drain stall (the m97 killer). 1 barrier/tile (vs 4-8) lets waves drift so
// one wave's MFMA overlaps another's LDS read burst (un-jams the LDS pipe).
// Hazards: stage->nxt issued after the sync that retires all reads of nxt's old
// tile (per-wave lgkmcnt(0) precedes barrier); reads of par validated because
// every wave drains its own vmcnt before the barrier.
__global__ __launch_bounds__(512, 2) void k_gemm256(
    const unsigned short* __restrict__ A, const unsigned short* __restrict__ Bw,
    unsigned short* __restrict__ qb, unsigned short* __restrict__ kb,
    unsigned short* __restrict__ vt,
    const float* __restrict__ cosT, const float* __restrict__ sinT)
{
  __shared__ __attribute__((aligned(16))) char smem[131072];
  const int tid = threadIdx.x, l = tid & 63, w = tid >> 6;
  const int g = l >> 4, c = l & 15;
  const int m0 = blockIdx.x * 256, n0 = blockIdx.y * 256;
  const int wr = w >> 2, wc = w & 3;
  const char* gA = (const char*)A;
  const char* gB = (const char*)Bw;

  // staging descriptors: 4 x 16B per thread per 32KB unit; inverse of layout
  int dstP[4]; size_t aoff[4], boff[4];
#pragma unroll
  for (int j = 0; j < 4; ++j) {
    int P = j*8192 + tid*16;
    int row = P >> 7;                        // 0..255
    int kc = ((P & 127) ^ ((row & 7) << 4)) >> 1;
    dstP[j] = P;
    aoff[j] = ((size_t)(m0 + row) * KDIM + kc) * 2;
    boff[j] = ((size_t)(n0 + row) * KDIM + kc) * 2;
  }

  // frag-read constants: af[mi] at aBase + mi*2048 + xterm(kk); bk[ni] likewise
  const int aBase = (wr*128 + c) * 128;
  const int bBase = 32768 + (wc*64 + c) * 128;
  const int xsw = (c & 7) << 4;

  f32x4 acc[8][4];
#pragma unroll
  for (int i = 0; i < 8; ++i)
#pragma unroll
    for (int j = 0; j < 4; ++j) acc[i][j] = (f32x4){0.f,0.f,0.f,0.f};

  // prologue: stage tile 0 into parity 0
#pragma unroll
  for (int j = 0; j < 4; ++j) {
    gld_lds16(gA + aoff[j], smem + dstP[j]);
    gld_lds16(gB + boff[j], smem + 32768 + dstP[j]);
  }

  for (int t = 0; t < 16; ++t) {
    const int par = (t & 1) << 16;
    const int nxt = par ^ 65536;

    __syncthreads();   // drains last tile's stages (old -> cheap) + orders LDS

    if (t + 1 < 16) {
      const size_t ko = (size_t)(t + 1) * 128;
#pragma unroll
      for (int j = 0; j < 4; ++j) {
        gld_lds16(gA + aoff[j] + ko, smem + nxt + dstP[j]);
        gld_lds16(gB + boff[j] + ko, smem + nxt + 32768 + dstP[j]);
      }
    }

#pragma unroll
    for (int kk = 0; kk < 2; ++kk) {
      const int xt = (kk*64 + g*16) ^ xsw;
      bf16x8 bk[4], af[8];
#pragma unroll
      for (int ni = 0; ni < 4; ++ni)
        bk[ni] = *(const bf16x8*)(smem + par + bBase + ni*2048 + xt);
#pragma unroll
      for (int mi = 0; mi < 8; ++mi)
        af[mi] = *(const bf16x8*)(smem + par + aBase + mi*2048 + xt);
      __builtin_amdgcn_s_setprio(1);
#pragma unroll
      for (int mi = 0; mi < 8; ++mi)
#pragma unroll
        for (int ni = 0; ni < 4; ++ni)
          acc[mi][ni] = __builtin_amdgcn_mfma_f32_16x16x32_bf16(af[mi], bk[ni], acc[mi][ni], 0, 0, 0);
      __builtin_amdgcn_s_setprio(0);
    }
  }

  // epilogue: fused RoPE; C layout: col = lane&15, row = g*4 + r
#pragma unroll
  for (int mi = 0; mi < 8; ++mi) {
#pragma unroll
    for (int ni = 0; ni < 4; ++ni) {
      const int mrow0 = m0 + wr*128 + mi*16 + g*4;
      const int ncol  = n0 + wc*64 + ni*16 + c;
      const int which = ncol >> 10;          // 0=q 1=k 2=v
      const int d = ncol & 1023, h = d >> 6, dd = d & 63;
      const int b = mrow0 >> 11, t0 = mrow0 & 2047;
      if (which == 2) {
        ushort4 o;
        o.x = f2bf(acc[mi][ni][0]); o.y = f2bf(acc[mi][ni][1]);
        o.z = f2bf(acc[mi][ni][2]); o.w = f2bf(acc[mi][ni][3]);
        *(ushort4*)(vt + ((size_t)((b*H_ + h)*D_ + dd))*T_ + t0) = o;
      } else {
#pragma unroll
        for (int r = 0; r < 4; ++r) {
          float val = acc[mi][ni][r];
          float partner = __shfl_xor(val, 1);          // value at dd^1 (lane^1)
          float rot = (dd & 1) ? partner : -partner;   // interleaved rotate_half
          float cv = cosT[(t0 + r)*64 + dd], sv = sinT[(t0 + r)*64 + dd];
          float o = val*cv + rot*sv;
          size_t oidx = (((size_t)(b*H_ + h))*T_ + (t0 + r))*D_ + dd;
          // q pre-scale: 1/sqrt(64) * log2(e)  (softmax done in exp2 domain)
          if (which == 0) qb[oidx] = f2bf(o * 0.180336879f);
          else            kb[oidx] = f2bf(o);
        }
      }
    }
  }
}

// ---------------------------------------------------------------- GEMM (NT, bf16), 128x128
// (unchanged proven template; output projection, EPI=1)
template<int EPI>
__global__ __launch_bounds__(256) void k_gemm(
    const unsigned short* __restrict__ A, const unsigned short* __restrict__ Bw,
    unsigned short* __restrict__ qb, unsigned short* __restrict__ kb,
    unsigned short* __restrict__ vt,
    const float* __restrict__ cosT, const float* __restrict__ sinT,
    float* __restrict__ outF)
{
  __shared__ __attribute__((aligned(16))) char smem[32768];  // A:16K B:16K
  const int tid = threadIdx.x, l = tid & 63, w = tid >> 6;
  const int g = l >> 4, c = l & 15;
  const int m0 = blockIdx.x * 128, n0 = blockIdx.y * 128;
  const int wr = w >> 1, wc = w & 1;

  const char* srcA[4]; const char* srcB[4]; int dstP[4];
#pragma unroll
  for (int j = 0; j < 4; ++j) {
    int P = w*4096 + j*1024 + l*16;
    int row = P >> 7;
    int Lb = P ^ ((row & 7) << 4);
    int col = (Lb & 127) >> 1;
    dstP[j] = P;
    srcA[j] = (const char*)A  + ((size_t)(m0 + row) * KDIM + col) * 2;
    srcB[j] = (const char*)Bw + ((size_t)(n0 + row) * KDIM + col) * 2;
  }

  f32x4 acc[4][4];
#pragma unroll
  for (int i = 0; i < 4; ++i)
#pragma unroll
    for (int j = 0; j < 4; ++j) acc[i][j] = (f32x4){0.f,0.f,0.f,0.f};

  for (int kt = 0; kt < KDIM; kt += 64) {
#pragma unroll
    for (int j = 0; j < 4; ++j) {
      gld_lds16(srcA[j] + kt*2, smem + dstP[j]);
      gld_lds16(srcB[j] + kt*2, smem + 16384 + dstP[j]);
    }
    __syncthreads();
#pragma unroll
    for (int kk = 0; kk < 2; ++kk) {
      bf16x8 af[4], bw4[4];
#pragma unroll
      for (int mi = 0; mi < 4; ++mi) {
        int row = wr*64 + mi*16 + c;
        int Lb = row*128 + (kk*32 + g*8)*2;
        af[mi] = *(const bf16x8*)(smem + (Lb ^ ((row & 7) << 4)));
      }
#pragma unroll
      for (int ni = 0; ni < 4; ++ni) {
        int row = wc*64 + ni*16 + c;
        int Lb = row*128 + (kk*32 + g*8)*2;
        bw4[ni] = *(const bf16x8*)(smem + 16384 + (Lb ^ ((row & 7) << 4)));
      }
#pragma unroll
      for (int mi = 0; mi < 4; ++mi)
#pragma unroll
        for (int ni = 0; ni < 4; ++ni)
          acc[mi][ni] = __builtin_amdgcn_mfma_f32_16x16x32_bf16(af[mi], bw4[ni], acc[mi][ni], 0, 0, 0);
    }
    __syncthreads();
  }

#pragma unroll
  for (int mi = 0; mi < 4; ++mi) {
#pragma unroll
    for (int ni = 0; ni < 4; ++ni) {
      const int mrow0 = m0 + wr*64 + mi*16 + g*4;
      const int ncol  = n0 + wc*64 + ni*16 + c;
      if (EPI == 1) {
#pragma unroll
        for (int r = 0; r < 4; ++r)
          outF[(size_t)(mrow0 + r) * 1024 + ncol] = acc[mi][ni][r];
      } else {
        const int which = ncol >> 10;
        const int d = ncol & 1023, h = d >> 6, dd = d & 63;
        const int b = mrow0 >> 11, t0 = mrow0 & 2047;
        if (which == 2) {
          ushort4 o;
          o.x = f2bf(acc[mi][ni][0]); o.y = f2bf(acc[mi][ni][1]);
          o.z = f2bf(acc[mi][ni][2]); o.w = f2bf(acc[mi][ni][3]);
          *(ushort4*)(vt + ((size_t)((b*H_ + h)*D_ + dd))*T_ + t0) = o;
        } else {
#pragma unroll
          for (int r = 0; r < 4; ++r) {
            float val = acc[mi][ni][r];
            float partner = __shfl_xor(val, 1);
            float rot = (dd & 1) ? partner : -partner;
            float cv = cosT[(t0 + r)*64 + dd], sv = sinT[(t0 + r)*64 + dd];
            float o = val*cv + rot*sv;
            size_t oidx = (((size_t)(b*H_ + h))*T_ + (t0 + r))*D_ + dd;
            if (which == 0) qb[oidx] = f2bf(o * 0.180336879f);
            else            kb[oidx] = f2bf(o);
          }
        }
      }
    }
  }
}

// ---------------------------------------------------------------- flash attention
// (unchanged from R14 passing kernel: 8 waves x 16 q-rows, XCD grid, 3-deep KV)
__global__ __launch_bounds__(512) void k_attn(
    const unsigned short* __restrict__ qb, const unsigned short* __restrict__ kb,
    const unsigned short* __restrict__ vt, unsigned short* __restrict__ yb)
{
  __shared__ __attribute__((aligned(16))) char smem[65536]; // 3x(K8K+V8K) + P:16K
  const int tid = threadIdx.x, l = tid & 63, w = tid >> 6;  // w in 0..7
  const int g = l >> 4, c = l & 15;
  const int bh = blockIdx.x;                 // x = bh -> XCD locality
  const int pidx = blockIdx.y;               // pair index 0..7
  const size_t bhO = (size_t)bh * T_ * D_;
  const int pbase = 49152 + w*2048;          // per-wave 2 KB P region
  const int b = bh >> 4, h = bh & 15;

  bf16x8 vones;
#pragma unroll
  for (int i = 0; i < 8; ++i) vones[i] = (short)0x3F80;   // bf16 1.0

  const char* srcK; const char* srcV; int dstP2;
  {
    int P = w*1024 + l*16;                 // [0, 8192)
    int row = P >> 7;
    int Lb = P ^ ((row & 7) << 4);
    int col = (Lb & 127) >> 1;
    dstP2 = P;
    srcK = (const char*)(kb + bhO) + ((size_t)row*D_ + col)*2;   // + kv0*128B
    srcV = (const char*)(vt + bhO) + ((size_t)row*T_ + col)*2;   // + kv0*2B
  }

  for (int half = 0; half < 2; ++half) {
    const int qt = half ? pidx : (15 - pidx);
    const int q0 = qt * 128;
    const int q0w = q0 + w*16;             // this wave's 16 q rows

    bf16x8 aq[2];
#pragma unroll
    for (int kc = 0; kc < 2; ++kc)
      aq[kc] = *(const bf16x8*)(qb + bhO + (size_t)(q0w + c)*D_ + kc*32 + g*8);

    f32x4 po[4];
    f32x4 ls;
    float mrun = -1e30f;
#pragma unroll
    for (int nd = 0; nd < 4; ++nd) po[nd] = (f32x4){0.f,0.f,0.f,0.f};
    ls = (f32x4){0.f,0.f,0.f,0.f};

    const int nkt = (q0 + 128) >> 6;       // = 2(qt+1), always >= 2

    gld_lds16(srcK, smem + dstP2);
    gld_lds16(srcV, smem + 8192 + dstP2);
    gld_lds16(srcK + (size_t)64*128, smem + 16384 + dstP2);
    gld_lds16(srcV + (size_t)64*2,   smem + 16384 + 8192 + dstP2);
    asm volatile("s_waitcnt vmcnt(2)" ::: "memory");
    __builtin_amdgcn_s_barrier();
    __builtin_amdgcn_sched_barrier(0);

    int rd = 0;                            // buffer index = it % 3
    for (int it = 0; it < nkt; ++it) {
      const int kv0 = it * 64;
      const int cur = rd * 16384;

      if (it + 2 < nkt) {
        int wi = rd + 2; if (wi >= 3) wi -= 3;
        const int wb = wi * 16384;
        gld_lds16(srcK + (size_t)(kv0 + 128) * 128, smem + wb + dstP2);
        gld_lds16(srcV + (size_t)(kv0 + 128) * 2,   smem + wb + 8192 + dstP2);
      }

      if (kv0 < q0w + 16) {
        f32x4 st[4];
#pragma unroll
        for (int ni = 0; ni < 4; ++ni) st[ni] = (f32x4){0.f,0.f,0.f,0.f};
        __builtin_amdgcn_s_setprio(1);
#pragma unroll
        for (int kk = 0; kk < 2; ++kk) {
          bf16x8 bk[4];
#pragma unroll
          for (int ni = 0; ni < 4; ++ni) {
            int kn = ni*16 + c;
            int Lb = kn*128 + (kk*32 + g*8)*2;
            bk[ni] = *(const bf16x8*)(smem + cur + (Lb ^ ((kn & 7) << 4)));
          }
#pragma unroll
          for (int ni = 0; ni < 4; ++ni)
            st[ni] = __builtin_amdgcn_mfma_f32_16x16x32_bf16(bk[ni], aq[kk], st[ni], 0, 0, 0);
        }
        __builtin_amdgcn_s_setprio(0);

        if (kv0 + 64 > q0w) {
          const int qq = q0w + c;
#pragma unroll
          for (int ni = 0; ni < 4; ++ni)
#pragma unroll
            for (int r = 0; r < 4; ++r) {
              int kvv = kv0 + ni*16 + g*4 + r;
              if (kvv > qq) st[ni][r] = -1e30f;
            }
        }

        {
          float mn[4];
#pragma unroll
          for (int ni = 0; ni < 4; ++ni)
            mn[ni] = fmaxf(fmaxf(st[ni][0], st[ni][1]), fmaxf(st[ni][2], st[ni][3]));
          float mt = fmaxf(fmaxf(mn[0], mn[1]), fmaxf(mn[2], mn[3]));
          mt = fmaxf(mt, __shfl_xor(mt, 16));
          mt = fmaxf(mt, __shfl_xor(mt, 32));
          float m_use = mrun;
          if (__any(mt > m_use + 8.f)) {
            float mnew = fmaxf(m_use, mt);
            float alpha = exp2_fast(m_use - mnew);
            mrun = mnew;
            m_use = mnew;
#pragma unroll
            for (int r = 0; r < 4; ++r) ls[r] *= alpha;
#pragma unroll
            for (int nd = 0; nd < 4; ++nd)
#pragma unroll
              for (int r = 0; r < 4; ++r) po[nd][r] *= alpha;
          }
#pragma unroll
          for (int ni = 0; ni < 4; ++ni)
#pragma unroll
            for (int r = 0; r < 4; ++r)
              st[ni][r] = exp2_fast(st[ni][r] - m_use);
        }

        {
          const int row = c;
          const int sw = (row & 7) << 4;
          const int rb = pbase + row*128;
#pragma unroll
          for (int ni = 0; ni < 4; ++ni) {
            unsigned u0, u1;
            asm("v_cvt_pk_bf16_f32 %0, %1, %2" : "=v"(u0) : "v"(st[ni][0]), "v"(st[ni][1]));
            asm("v_cvt_pk_bf16_f32 %0, %1, %2" : "=v"(u1) : "v"(st[ni][2]), "v"(st[ni][3]));
            int Lb = (ni*16 + g*4) * 2;
            uint2 uu; uu.x = u0; uu.y = u1;
            *(uint2*)(smem + rb + (Lb ^ sw)) = uu;
          }
        }

        __builtin_amdgcn_s_setprio(1);
#pragma unroll
        for (int kk = 0; kk < 2; ++kk) {
          bf16x8 pb;
          {
            int pr = c;
            int Lb = pr*128 + (kk*32 + g*8)*2;
            pb = *(const bf16x8*)(smem + pbase + (Lb ^ ((pr & 7) << 4)));
          }
          ls = __builtin_amdgcn_mfma_f32_16x16x32_bf16(vones, pb, ls, 0, 0, 0);
          bf16x8 bv[4];
#pragma unroll
          for (int nd = 0; nd < 4; ++nd) {
            int vr = nd*16 + c;
            int Lb = vr*128 + (kk*32 + g*8)*2;
            bv[nd] = *(const bf16x8*)(smem + cur + 8192 + (Lb ^ ((vr & 7) << 4)));
          }
#pragma unroll
          for (int nd = 0; nd < 4; ++nd)
            po[nd] = __builtin_amdgcn_mfma_f32_16x16x32_bf16(bv[nd], pb, po[nd], 0, 0, 0);
        }
        __builtin_amdgcn_s_setprio(0);
      }

      if (it + 1 < nkt) {
        if (it + 2 < nkt) { asm volatile("s_waitcnt vmcnt(2)" ::: "memory"); }
        else              { asm volatile("s_waitcnt vmcnt(0)" ::: "memory"); }
      }
      __builtin_amdgcn_s_barrier();
      __builtin_amdgcn_sched_barrier(0);
      rd = (rd == 2) ? 0 : rd + 1;
    }

    {
      float inv = 1.f / ls[0];
      int t = q0w + c;
#pragma unroll
      for (int nd = 0; nd < 4; ++nd) {
        ushort4 o;
        o.x = f2bf(po[nd][0] * inv);
        o.y = f2bf(po[nd][1] * inv);
        o.z = f2bf(po[nd][2] * inv);
        o.w = f2bf(po[nd][3] * inv);
        *(ushort4*)(yb + ((size_t)b*T_ + t)*C_ + h*64 + nd*16 + g*4) = o;
      }
    }
  }
}

// ---------------------------------------------------------------- launcher
extern "C" void kernel_launch(void* const* d_in, const int* in_sizes, int n_in,
                              void* d_out, int out_size, void* d_ws, size_t ws_size,
                              hipStream_t stream)
{
  const float* x  = (const float*)d_in[0];
  const float* Wq = (const float*)d_in[1];
  const float* Wk = (const float*)d_in[2];
  const float* Wv = (const float*)d_in[3];
  const float* Wp = (const float*)d_in[4];
  const int*   sp = (const int*)d_in[5];
  float* out = (float*)d_out;

  char* ws = (char*)d_ws;
  unsigned short* xb   = (unsigned short*)(ws);                  // 16 MB
  unsigned short* wcat = (unsigned short*)(ws + 16777216);       // 6 MB [Wq;Wk;Wv]
  unsigned short* wpb  = (unsigned short*)(ws + 23068672);       // 2 MB
  unsigned short* qb   = (unsigned short*)(ws + 25165824);       // 16 MB (B,H,T,D)
  unsigned short* kb   = (unsigned short*)(ws + 41943040);       // 16 MB (B,H,T,D)
  unsigned short* vt   = (unsigned short*)(ws + 58720256);       // 16 MB (B,H,D,T)
  unsigned short* yb   = (unsigned short*)(ws + 75497472);       // 16 MB (B*T, C)
  float* cosT = (float*)(ws + 92274688);                         // 512 KB [T][D]
  float* sinT = (float*)(ws + 92798976);                         // 512 KB [T][D]

  k_convert<<<dim3(2048), dim3(256), 0, stream>>>(x, Wq, Wk, Wv, Wp, xb, wcat, wpb);
  k_rope_tab<<<dim3(512), dim3(256), 0, stream>>>(sp, cosT, sinT);
  k_gemm256<<<dim3(32, 12), dim3(512), 0, stream>>>(xb, wcat, qb, kb, vt, cosT, sinT);
  k_attn<<<dim3(64, 8), dim3(512), 0, stream>>>(qb, kb, vt, yb);
  k_gemm<1><<<dim3(64, 8), dim3(256), 0, stream>>>(yb, wpb, nullptr, nullptr, nullptr, nullptr, nullptr, out);
}